// Round 5
// baseline (292.054 us; speedup 1.0000x reference)
//
#include <hip/hip_runtime.h>

// Pfaffian of 128 gathered 128x128 skew-symmetric f32 matrices, Parlett-Reid
// LTL^T, one 256-thread block per matrix.
//
// NUMERICS LEDGER (rounds 0-4):
//   r0/r4: exact f64, two independent structures -> BIT-IDENTICAL absmax
//          0.0908 vs np ref => conceptual pipeline certified; np ref is an
//          f32 trajectory at distance 0.0908 from exact.
//   r1/r2: FMA-free f32 (pragma == __f*_rn, bit-identical) -> 0.1557 =
//          independent-walk distance => np ref is NOT the plain
//          mul/mul/add/sub schedule. A numpy transcription would be; hence
//          ref values came from the JAX fn on XLA CPU f32, which FMA-fuses:
//            tmp = fma(tau_i, col_j, A);  A' = fma(-col_i, tau_j, tmp)
//   THIS ROUND: replicate that fused schedule exactly (__fmaf_rn), IEEE
//   divide for tau, f32 pf product in step order.
//
// Layout: thread t owns row r = t & 127, column half h = t >> 7 (wave-uniform
// so whole waves retire as the trailing block shrinks), 64 f32 registers.

__global__ __launch_bounds__(256) void pfaffian_kernel(
    const float* __restrict__ x,    // [128, 128]
    const float* __restrict__ F,    // [32640] packed strict lower triangle of 256x256
    float* __restrict__ out)        // [128]
{
    const int b    = blockIdx.x;
    const int t    = threadIdx.x;
    const int lane = t & 63;
    const int wave = t >> 6;

    __shared__ int   idx_sh[128];
    __shared__ int   wtot[4];
    __shared__ float tau_s[128];    // raw row k of A
    __shared__ float taud_s[128];   // tau = row_k / pivot (masked, IEEE f32 div)
    __shared__ float col_s[128];    // column k+1 of A

    // ---- occupancy -> sorted index list (exactly 128 set bits) ----
    const float xv  = x[b * 128 + (t & 127)];
    const bool  pos = xv > 0.0f;
    const bool  o   = (t < 128) ? pos : !pos;

    const unsigned long long m = __ballot(o);
    const int rank = __popcll(m & ((1ull << lane) - 1ull));
    if (lane == 63) wtot[wave] = rank + (o ? 1 : 0);
    __syncthreads();
    int off = 0;
#pragma unroll
    for (int w = 0; w < 4; ++w)
        if (w < wave) off += wtot[w];
    if (o) idx_sh[off + rank] = t;
    __syncthreads();

    // ---- gather A[r][c] = F_full[idx[r]][idx[c]] (exact sign work) ----
    const int h     = t >> 7;        // column half (wave-uniform)
    const int r     = t & 127;       // owned row
    const int cbase = h * 64;

    const int ii = idx_sh[r];
    float A[64];
#pragma unroll
    for (int c = 0; c < 64; ++c) {
        const int jj = idx_sh[cbase + c];
        const int hi = ii > jj ? ii : jj;
        const int lo = ii > jj ? jj : ii;
        float v = (ii == jj) ? 0.0f : F[(hi * (hi - 1)) / 2 + lo];
        A[c] = (ii < jj) ? -v : v;
    }
    // No barrier needed: tau_s/col_s are distinct from idx_sh and are
    // barrier-protected before first read.

    // ---- 64 elimination steps ----
    float pf = 1.0f;
    for (int i = 0; i < 64; ++i) {
        const int k   = 2 * i;
        const int kp1 = k + 1;

        // Phase A: publish raw row k (both halves) and column k+1 (rows > k+1)
        if (r == k) {
#pragma unroll
            for (int c = 0; c < 64; ++c) tau_s[cbase + c] = A[c];
        }
        if ((kp1 >> 6) == h && r > kp1) col_s[r] = A[kp1 & 63];
        __syncthreads();

        const float pivot = tau_s[kp1];   // A[k][k+1], pre-update
        pf = __fmul_rn(pf, pivot);        // f32, step order (matches scan)

        // Phase B: per-element IEEE f32 division, one per thread t<128
        if (t < 128) taud_s[t] = (t > kp1) ? __fdiv_rn(tau_s[t], pivot) : 0.0f;
        __syncthreads();

        // Phase C: rank-2 update, XLA-CPU fused schedule:
        //   tmp = fma(tau_i, col_j, A);  A' = fma(-col_i, tau_j, tmp)
        if (r > kp1 && (k + 2) < cbase + 64) {
            const float tau_r  = taud_s[r];
            const float ncol_r = -col_s[r];
#pragma unroll
            for (int c = 0; c < 64; ++c) {
                const int cg = cbase + c;
                if (cg > kp1) {  // wave-uniform (k uniform, cg compile-time)
                    const float tmp = __fmaf_rn(tau_r, col_s[cg], A[c]);
                    A[c] = __fmaf_rn(ncol_r, taud_s[cg], tmp);
                }
            }
        }
        __syncthreads();
    }

    if (t == 0) out[b] = pf;
}

extern "C" void kernel_launch(void* const* d_in, const int* in_sizes, int n_in,
                              void* d_out, int out_size, void* d_ws, size_t ws_size,
                              hipStream_t stream) {
    const float* x = (const float*)d_in[0];   // [128*128]
    const float* F = (const float*)d_in[1];   // [32640]
    float* out     = (float*)d_out;           // [128]
    (void)in_sizes; (void)n_in; (void)out_size; (void)d_ws; (void)ws_size;

    pfaffian_kernel<<<128, 256, 0, stream>>>(x, F, out);
}

// Round 6
// 262.084 us; speedup vs baseline: 1.1144x; 1.1144x over previous
//
#include <hip/hip_runtime.h>

// Pfaffian of 128 gathered 128x128 skew-symmetric f32 matrices, Parlett-Reid
// LTL^T, one 256-thread block per matrix, 8x8 register sub-block per thread.
//
// NUMERICS LEDGER (rounds 0-5): np ref is the XLA-CPU f32 trajectory with
// FMA-fused rank-2 update:
//     tmp = fma(tau_i, col_j, A);  A' = fma(-col_i, tau_j, tmp)
// tau = IEEE f32 divide, pf = f32 product in step order. Round 5 PASSED
// (absmax 0.0234 < 0.0684) with exactly this schedule; this round preserves
// it bit-for-bit (__fmaf_rn/__fdiv_rn/__fmul_rn on identical values) while
// restructuring for latency:
//   r5: per-column runtime branches serialized ds_read latency -> 9.5k
//       cyc/step (255 us, VALUBusy 2.6%).
//   now: 8x8 blocks -> 8 batched ds_read_b128 per thread per step,
//       branch-free masked update (dead indices staged as exact 0.0f so the
//       FMA update is the identity on dead entries, which are never read),
//       2 barriers/step (next pivot published by its owner during the
//       update; row-k publishers do their own 8 divides).

__global__ __launch_bounds__(256) void pfaffian_kernel(
    const float* __restrict__ x,    // [128, 128]
    const float* __restrict__ F,    // [32640] packed strict lower tri of 256x256
    float* __restrict__ out)        // [128]
{
    const int b    = blockIdx.x;
    const int t    = threadIdx.x;
    const int lane = t & 63;
    const int wave = t >> 6;

    __shared__ int idx_sh[128];
    __shared__ int wtot[4];
    __shared__ __align__(16) float taud_s[128];  // tau = row_k / pivot (0 on dead idx)
    __shared__ __align__(16) float col_s[128];   // col k+1 (0 on dead idx)
    __shared__ float pivot_sh;                   // A[k][k+1] for the current step

    // ---- occupancy -> sorted index list (certified in rounds 0-5) ----
    const float xv  = x[b * 128 + (t & 127)];
    const bool  pos = xv > 0.0f;
    const bool  o   = (t < 128) ? pos : !pos;

    const unsigned long long m = __ballot(o);
    const int rank = __popcll(m & ((1ull << lane) - 1ull));
    if (lane == 63) wtot[wave] = rank + (o ? 1 : 0);
    __syncthreads();
    int off = 0;
#pragma unroll
    for (int w = 0; w < 4; ++w)
        if (w < wave) off += wtot[w];
    if (o) idx_sh[off + rank] = t;
    __syncthreads();

    // ---- 8x8 block ownership ----
    const int r8   = t >> 4;        // row group: rows [r8*8, r8*8+8)
    const int c8   = t & 15;        // col group: cols [c8*8, c8*8+8)
    const int row0 = r8 * 8;
    const int col0 = c8 * 8;

    int ri[8], ci[8];
#pragma unroll
    for (int a = 0; a < 8; ++a) ri[a] = idx_sh[row0 + a];
#pragma unroll
    for (int c = 0; c < 8; ++c) ci[c] = idx_sh[col0 + c];

    // ---- gather A[a][c] = F_full[ri[a]][ci[c]] (exact sign work) ----
    float A[8][8];
#pragma unroll
    for (int a = 0; a < 8; ++a) {
        const int ii = ri[a];
#pragma unroll
        for (int c = 0; c < 8; ++c) {
            const int jj = ci[c];
            const int hi = ii > jj ? ii : jj;
            const int lo = ii > jj ? jj : ii;
            float v = (ii == jj) ? 0.0f : F[(hi * (hi - 1)) / 2 + lo];
            A[a][c] = (ii < jj) ? -v : v;
        }
    }

    // seed pivot for step 0: A[0][1], owned by thread 0 (r8=0, c8=0)
    if (t == 0) pivot_sh = A[0][1];
    __syncthreads();

    // ---- 64 elimination steps, 2 barriers each ----
    float pf = 1.0f;
    for (int i = 0; i < 64; ++i) {
        const int k   = 2 * i;
        const int kp1 = k + 1;

        const float piv = pivot_sh;        // ordered by prev-step/pre-loop barrier
        pf = __fmul_rn(pf, piv);           // f32 product in step order

        // Phase A: row-k owners publish tau = row_k / piv (dead idx -> 0);
        //          col-(k+1) owners publish the column (dead idx -> 0)
        if (r8 == (k >> 3)) {
            const int a = k & 7;
#pragma unroll
            for (int j = 0; j < 8; ++j) {
                const int cj = col0 + j;
                taud_s[cj] = (cj > kp1) ? __fdiv_rn(A[a][j], piv) : 0.0f;
            }
        }
        if (c8 == (kp1 >> 3)) {
            const int cc = kp1 & 7;
#pragma unroll
            for (int j = 0; j < 8; ++j) {
                const int rj = row0 + j;
                col_s[rj] = (rj > kp1) ? A[j][cc] : 0.0f;
            }
        }
        __syncthreads();

        // Phase B: branch-free masked rank-2 update of the 8x8 block.
        // Wave-uniform early-out once all of this wave's rows are dead.
        if (wave * 32 + 31 > kp1) {
            float4 tr0 = *(const float4*)&taud_s[row0];
            float4 tr1 = *(const float4*)&taud_s[row0 + 4];
            float4 cr0 = *(const float4*)&col_s[row0];
            float4 cr1 = *(const float4*)&col_s[row0 + 4];
            float4 tc0 = *(const float4*)&taud_s[col0];
            float4 tc1 = *(const float4*)&taud_s[col0 + 4];
            float4 cc0 = *(const float4*)&col_s[col0];
            float4 cc1 = *(const float4*)&col_s[col0 + 4];

            float tr[8] = {tr0.x, tr0.y, tr0.z, tr0.w, tr1.x, tr1.y, tr1.z, tr1.w};
            float cr[8] = {cr0.x, cr0.y, cr0.z, cr0.w, cr1.x, cr1.y, cr1.z, cr1.w};
            float tc[8] = {tc0.x, tc0.y, tc0.z, tc0.w, tc1.x, tc1.y, tc1.z, tc1.w};
            float cc[8] = {cc0.x, cc0.y, cc0.z, cc0.w, cc1.x, cc1.y, cc1.z, cc1.w};

            float ncr[8];
#pragma unroll
            for (int a = 0; a < 8; ++a) ncr[a] = -cr[a];

#pragma unroll
            for (int a = 0; a < 8; ++a) {
#pragma unroll
                for (int c = 0; c < 8; ++c) {
                    const float tmp = __fmaf_rn(tr[a], cc[c], A[a][c]);
                    A[a][c] = __fmaf_rn(ncr[a], tc[c], tmp);
                }
            }

            // publish next step's pivot A[k+2][k+3] (owner is always alive)
            if (i < 63 && r8 == ((k + 2) >> 3) && c8 == ((k + 3) >> 3)) {
                pivot_sh = A[(k + 2) & 7][(k + 3) & 7];
            }
        }
        __syncthreads();
    }

    if (t == 0) out[b] = pf;
}

extern "C" void kernel_launch(void* const* d_in, const int* in_sizes, int n_in,
                              void* d_out, int out_size, void* d_ws, size_t ws_size,
                              hipStream_t stream) {
    const float* x = (const float*)d_in[0];   // [128*128]
    const float* F = (const float*)d_in[1];   // [32640]
    float* out     = (float*)d_out;           // [128]
    (void)in_sizes; (void)n_in; (void)out_size; (void)d_ws; (void)ws_size;

    pfaffian_kernel<<<128, 256, 0, stream>>>(x, F, out);
}

// Round 7
// 261.027 us; speedup vs baseline: 1.1189x; 1.0040x over previous
//
#include <hip/hip_runtime.h>

// Pfaffian of 128 gathered 128x128 skew-symmetric f32 matrices, Parlett-Reid
// LTL^T, one 256-thread block per matrix, 8x8 register sub-block per thread.
//
// NUMERICS LEDGER (rounds 0-6): np ref is the XLA-CPU f32 trajectory with
// FMA-fused rank-2 update:
//     tmp = fma(tau_i, col_j, A);  A' = fma(-col_i, tau_j, tmp)
// tau = IEEE f32 divide, pf = f32 product in step order. Rounds 5/6 PASSED
// with absmax 0.0234375; this schedule must not change.
//
// PERF LEDGER:
//   r5: 255 us. r6 (8x8 blocks, 2 barriers/step): 227 us — nearly identical
//   because BOTH were register-spill bound: VGPR_Count=64 while A needs 64
//   VGPRs alone -> A spilled to scratch; WRITE_SIZE=8196 KB == exactly one
//   full A write-back (128*256*64*4 B). Per-step scratch reloads through
//   L1/L2 (~50-200 cyc, dependency-serialized) -> ~8.5k cyc/step.
//   r7 fix: __launch_bounds__(256, 1) lifts the VGPR cap (we have 0.5
//   blocks/CU — occupancy beyond 1 block/CU is worthless). A stays in
//   registers; arithmetic untouched.

__global__ __launch_bounds__(256, 1) void pfaffian_kernel(
    const float* __restrict__ x,    // [128, 128]
    const float* __restrict__ F,    // [32640] packed strict lower tri of 256x256
    float* __restrict__ out)        // [128]
{
    const int b    = blockIdx.x;
    const int t    = threadIdx.x;
    const int lane = t & 63;
    const int wave = t >> 6;

    __shared__ int idx_sh[128];
    __shared__ int wtot[4];
    __shared__ __align__(16) float taud_s[128];  // tau = row_k / pivot (0 on dead idx)
    __shared__ __align__(16) float col_s[128];   // col k+1 (0 on dead idx)
    __shared__ float pivot_sh;                   // A[k][k+1] for the current step

    // ---- occupancy -> sorted index list (certified in rounds 0-5) ----
    const float xv  = x[b * 128 + (t & 127)];
    const bool  pos = xv > 0.0f;
    const bool  o   = (t < 128) ? pos : !pos;

    const unsigned long long m = __ballot(o);
    const int rank = __popcll(m & ((1ull << lane) - 1ull));
    if (lane == 63) wtot[wave] = rank + (o ? 1 : 0);
    __syncthreads();
    int off = 0;
#pragma unroll
    for (int w = 0; w < 4; ++w)
        if (w < wave) off += wtot[w];
    if (o) idx_sh[off + rank] = t;
    __syncthreads();

    // ---- 8x8 block ownership ----
    const int r8   = t >> 4;        // row group: rows [r8*8, r8*8+8)
    const int c8   = t & 15;        // col group: cols [c8*8, c8*8+8)
    const int row0 = r8 * 8;
    const int col0 = c8 * 8;

    int ri[8], ci[8];
#pragma unroll
    for (int a = 0; a < 8; ++a) ri[a] = idx_sh[row0 + a];
#pragma unroll
    for (int c = 0; c < 8; ++c) ci[c] = idx_sh[col0 + c];

    // ---- gather A[a][c] = F_full[ri[a]][ci[c]] (exact sign work) ----
    float A[8][8];
#pragma unroll
    for (int a = 0; a < 8; ++a) {
        const int ii = ri[a];
#pragma unroll
        for (int c = 0; c < 8; ++c) {
            const int jj = ci[c];
            const int hi = ii > jj ? ii : jj;
            const int lo = ii > jj ? jj : ii;
            float v = (ii == jj) ? 0.0f : F[(hi * (hi - 1)) / 2 + lo];
            A[a][c] = (ii < jj) ? -v : v;
        }
    }

    // seed pivot for step 0: A[0][1], owned by thread 0 (r8=0, c8=0)
    if (t == 0) pivot_sh = A[0][1];
    __syncthreads();

    // ---- 64 elimination steps, 2 barriers each ----
    float pf = 1.0f;
    for (int i = 0; i < 64; ++i) {
        const int k   = 2 * i;
        const int kp1 = k + 1;

        const float piv = pivot_sh;        // ordered by prev-step/pre-loop barrier
        pf = __fmul_rn(pf, piv);           // f32 product in step order

        // Phase A: row-k owners publish tau = row_k / piv (dead idx -> 0);
        //          col-(k+1) owners publish the column (dead idx -> 0)
        if (r8 == (k >> 3)) {
            const int a = k & 7;
#pragma unroll
            for (int j = 0; j < 8; ++j) {
                const int cj = col0 + j;
                taud_s[cj] = (cj > kp1) ? __fdiv_rn(A[a][j], piv) : 0.0f;
            }
        }
        if (c8 == (kp1 >> 3)) {
            const int cc = kp1 & 7;
#pragma unroll
            for (int j = 0; j < 8; ++j) {
                const int rj = row0 + j;
                col_s[rj] = (rj > kp1) ? A[j][cc] : 0.0f;
            }
        }
        __syncthreads();

        // Phase B: branch-free masked rank-2 update of the 8x8 block.
        // Wave-uniform early-out once all of this wave's rows are dead.
        if (wave * 32 + 31 > kp1) {
            float4 tr0 = *(const float4*)&taud_s[row0];
            float4 tr1 = *(const float4*)&taud_s[row0 + 4];
            float4 cr0 = *(const float4*)&col_s[row0];
            float4 cr1 = *(const float4*)&col_s[row0 + 4];
            float4 tc0 = *(const float4*)&taud_s[col0];
            float4 tc1 = *(const float4*)&taud_s[col0 + 4];
            float4 cc0 = *(const float4*)&col_s[col0];
            float4 cc1 = *(const float4*)&col_s[col0 + 4];

            float tr[8] = {tr0.x, tr0.y, tr0.z, tr0.w, tr1.x, tr1.y, tr1.z, tr1.w};
            float cr[8] = {cr0.x, cr0.y, cr0.z, cr0.w, cr1.x, cr1.y, cr1.z, cr1.w};
            float tc[8] = {tc0.x, tc0.y, tc0.z, tc0.w, tc1.x, tc1.y, tc1.z, tc1.w};
            float cc[8] = {cc0.x, cc0.y, cc0.z, cc0.w, cc1.x, cc1.y, cc1.z, cc1.w};

            float ncr[8];
#pragma unroll
            for (int a = 0; a < 8; ++a) ncr[a] = -cr[a];

#pragma unroll
            for (int a = 0; a < 8; ++a) {
#pragma unroll
                for (int c = 0; c < 8; ++c) {
                    const float tmp = __fmaf_rn(tr[a], cc[c], A[a][c]);
                    A[a][c] = __fmaf_rn(ncr[a], tc[c], tmp);
                }
            }

            // publish next step's pivot A[k+2][k+3] (owner is always alive)
            if (i < 63 && r8 == ((k + 2) >> 3) && c8 == ((k + 3) >> 3)) {
                pivot_sh = A[(k + 2) & 7][(k + 3) & 7];
            }
        }
        __syncthreads();
    }

    if (t == 0) out[b] = pf;
}

extern "C" void kernel_launch(void* const* d_in, const int* in_sizes, int n_in,
                              void* d_out, int out_size, void* d_ws, size_t ws_size,
                              hipStream_t stream) {
    const float* x = (const float*)d_in[0];   // [128*128]
    const float* F = (const float*)d_in[1];   // [32640]
    float* out     = (float*)d_out;           // [128]
    (void)in_sizes; (void)n_in; (void)out_size; (void)d_ws; (void)ws_size;

    pfaffian_kernel<<<128, 256, 0, stream>>>(x, F, out);
}

// Round 8
// 102.385 us; speedup vs baseline: 2.8525x; 2.5495x over previous
//
#include <hip/hip_runtime.h>

// Pfaffian of 128 gathered 128x128 skew-symmetric f32 matrices, Parlett-Reid
// LTL^T, one 256-thread block per matrix, 8x8 register sub-block per thread.
//
// NUMERICS LEDGER (rounds 0-7): np ref is the XLA-CPU f32 trajectory with
// FMA-fused rank-2 update:
//     tmp = fma(tau_i, col_j, A);  A' = fma(-col_i, tau_j, tmp)
// tau = IEEE f32 divide (__fdiv_rn), pf = __fmul_rn product in step order.
// Rounds 5/6/7 PASSED with absmax 0.0234375; the schedule must not change.
//
// PERF LEDGER:
//   r5/r6/r7 all ~225 us, all with VGPR_Count=64 and WRITE_SIZE=8196 KB ==
//   exactly one full write-back of A (128*256*64*4 B): A lived in SCRATCH.
//   r7's __launch_bounds__(256,1) was a no-op (4 waves/block = 1 wave/EU is
//   already minimum) -> the spill is NOT occupancy-driven. Cause: DYNAMIC
//   indexing into A (A[k&7][j], A[j][kp1&7], A[(k+2)&7][(k+3)&7] with
//   runtime k) forces the local array to scratch regardless of VGPR budget.
//   r8 fix: unroll the step loop 4x — k&7 = 2s, kp1&7 = 2s+1, pivot idx
//   (2s+2)&7/(2s+3)&7 all become compile-time; runtime k survives only in
//   wave-uniform comparisons. A becomes register-resident.

__global__ __launch_bounds__(256, 1) void pfaffian_kernel(
    const float* __restrict__ x,    // [128, 128]
    const float* __restrict__ F,    // [32640] packed strict lower tri of 256x256
    float* __restrict__ out)        // [128]
{
    const int b    = blockIdx.x;
    const int t    = threadIdx.x;
    const int lane = t & 63;
    const int wave = t >> 6;

    __shared__ int idx_sh[128];
    __shared__ int wtot[4];
    __shared__ __align__(16) float taud_s[128];  // tau = row_k / pivot (0 on dead idx)
    __shared__ __align__(16) float col_s[128];   // col k+1 (0 on dead idx)
    __shared__ float pivot_sh;                   // A[k][k+1] for the current step

    // ---- occupancy -> sorted index list (certified in rounds 0-5) ----
    const float xv  = x[b * 128 + (t & 127)];
    const bool  pos = xv > 0.0f;
    const bool  o   = (t < 128) ? pos : !pos;

    const unsigned long long m = __ballot(o);
    const int rank = __popcll(m & ((1ull << lane) - 1ull));
    if (lane == 63) wtot[wave] = rank + (o ? 1 : 0);
    __syncthreads();
    int off = 0;
#pragma unroll
    for (int w = 0; w < 4; ++w)
        if (w < wave) off += wtot[w];
    if (o) idx_sh[off + rank] = t;
    __syncthreads();

    // ---- 8x8 block ownership ----
    const int r8   = t >> 4;        // row group: rows [r8*8, r8*8+8)
    const int c8   = t & 15;        // col group: cols [c8*8, c8*8+8)
    const int row0 = r8 * 8;
    const int col0 = c8 * 8;

    int ri[8], ci[8];
#pragma unroll
    for (int a = 0; a < 8; ++a) ri[a] = idx_sh[row0 + a];
#pragma unroll
    for (int c = 0; c < 8; ++c) ci[c] = idx_sh[col0 + c];

    // ---- gather A[a][c] = F_full[ri[a]][ci[c]] (exact sign work) ----
    float A[8][8];   // ALL indices below are compile-time -> register-resident
#pragma unroll
    for (int a = 0; a < 8; ++a) {
        const int ii = ri[a];
#pragma unroll
        for (int c = 0; c < 8; ++c) {
            const int jj = ci[c];
            const int hi = ii > jj ? ii : jj;
            const int lo = ii > jj ? jj : ii;
            float v = (ii == jj) ? 0.0f : F[(hi * (hi - 1)) / 2 + lo];
            A[a][c] = (ii < jj) ? -v : v;
        }
    }

    // seed pivot for step 0: A[0][1], owned by thread 0 (r8=0, c8=0)
    if (t == 0) pivot_sh = A[0][1];
    __syncthreads();

    // ---- 64 elimination steps; s unrolled so k&7 etc are compile-time ----
    float pf = 1.0f;
    for (int ib = 0; ib < 16; ++ib) {
#pragma unroll
        for (int s = 0; s < 4; ++s) {
            const int i   = ib * 4 + s;
            const int k   = 8 * ib + 2 * s;      // k & 7 == 2s (compile-time)
            const int kp1 = k + 1;               // kp1 & 7 == 2s+1 (compile-time)
            const int ka  = 2 * s;               // row index of row k in its block
            const int kc  = 2 * s + 1;           // col index of col k+1 in its block

            const float piv = pivot_sh;          // ordered by prev barrier
            pf = __fmul_rn(pf, piv);             // f32 product in step order

            // Phase A: row-k owners publish tau = row_k / piv (dead idx -> 0);
            //          col-(k+1) owners publish the column (dead idx -> 0)
            if (r8 == (k >> 3)) {
#pragma unroll
                for (int j = 0; j < 8; ++j) {
                    const int cj = col0 + j;
                    taud_s[cj] = (cj > kp1) ? __fdiv_rn(A[ka][j], piv) : 0.0f;
                }
            }
            if (c8 == (kp1 >> 3)) {
#pragma unroll
                for (int j = 0; j < 8; ++j) {
                    const int rj = row0 + j;
                    col_s[rj] = (rj > kp1) ? A[j][kc] : 0.0f;
                }
            }
            __syncthreads();

            // Phase B: branch-free masked rank-2 update of the 8x8 block.
            // Wave-uniform early-out once all of this wave's rows are dead.
            if (wave * 32 + 31 > kp1) {
                float4 tr0 = *(const float4*)&taud_s[row0];
                float4 tr1 = *(const float4*)&taud_s[row0 + 4];
                float4 cr0 = *(const float4*)&col_s[row0];
                float4 cr1 = *(const float4*)&col_s[row0 + 4];
                float4 tc0 = *(const float4*)&taud_s[col0];
                float4 tc1 = *(const float4*)&taud_s[col0 + 4];
                float4 cc0 = *(const float4*)&col_s[col0];
                float4 cc1 = *(const float4*)&col_s[col0 + 4];

                float tr[8] = {tr0.x, tr0.y, tr0.z, tr0.w, tr1.x, tr1.y, tr1.z, tr1.w};
                float cr[8] = {cr0.x, cr0.y, cr0.z, cr0.w, cr1.x, cr1.y, cr1.z, cr1.w};
                float tc[8] = {tc0.x, tc0.y, tc0.z, tc0.w, tc1.x, tc1.y, tc1.z, tc1.w};
                float cc[8] = {cc0.x, cc0.y, cc0.z, cc0.w, cc1.x, cc1.y, cc1.z, cc1.w};

                float ncr[8];
#pragma unroll
                for (int a = 0; a < 8; ++a) ncr[a] = -cr[a];

#pragma unroll
                for (int a = 0; a < 8; ++a) {
#pragma unroll
                    for (int c = 0; c < 8; ++c) {
                        const float tmp = __fmaf_rn(tr[a], cc[c], A[a][c]);
                        A[a][c] = __fmaf_rn(ncr[a], tc[c], tmp);
                    }
                }

                // publish next step's pivot A[k+2][k+3]; block-local indices
                // (2s+2)&7 / (2s+3)&7 are compile-time
                if (i < 63 && r8 == ((k + 2) >> 3) && c8 == ((k + 3) >> 3)) {
                    pivot_sh = A[(2 * s + 2) & 7][(2 * s + 3) & 7];
                }
            }
            __syncthreads();
        }
    }

    if (t == 0) out[b] = pf;
}

extern "C" void kernel_launch(void* const* d_in, const int* in_sizes, int n_in,
                              void* d_out, int out_size, void* d_ws, size_t ws_size,
                              hipStream_t stream) {
    const float* x = (const float*)d_in[0];   // [128*128]
    const float* F = (const float*)d_in[1];   // [32640]
    float* out     = (float*)d_out;           // [128]
    (void)in_sizes; (void)n_in; (void)out_size; (void)d_ws; (void)ws_size;

    pfaffian_kernel<<<128, 256, 0, stream>>>(x, F, out);
}

// Round 9
// 99.023 us; speedup vs baseline: 2.9493x; 1.0339x over previous
//
#include <hip/hip_runtime.h>

// Pfaffian of 128 gathered 128x128 skew-symmetric f32 matrices, Parlett-Reid
// LTL^T, one 256-thread block per matrix, 8x8 register sub-block per thread.
//
// NUMERICS LEDGER (rounds 0-8): np ref is the XLA-CPU f32 trajectory with
// FMA-fused rank-2 update:
//     tmp = fma(tau_i, col_j, A);  A' = fma(-col_i, tau_j, tmp)
// tau = IEEE f32 divide (__fdiv_rn), pf = __fmul_rn product in step order.
// Rounds 5-8 PASSED with absmax 0.0234375; this schedule must not change.
//
// PERF LEDGER:
//   r5/r6/r7 ~225 us: A in scratch (dynamic indexing -> spill; WRITE_SIZE
//     8196 KB = full A write-back). r8: 4x step-unroll made all A indices
//     compile-time -> 50.6 us/dispatch, WRITE_SIZE 4 KB, VALUBusy 8.5%.
//   r8 residual: ~1690/1850 cyc/step is sync latency — TWO __syncthreads
//     per step (full vmcnt/lgkmcnt drain + 4-wave rendezvous at 1 wave/SIMD,
//     nothing co-resident to hide it) + LDS round-trip + masked fdiv.
//   r9: ONE barrier/step. Double-buffered tau/col/piv (parity compile-time
//     under the unroll); next step's publishers update their own block and
//     publish DURING step i; next pivot forwarded in-register via __shfl
//     within the tau-publisher wave (lockstep, no sync). Dead waves skip the
//     whole body (stale dead-index buffer entries are never consumed — all
//     future tau/col/piv touch indices > k+1 only; publish masks keep the
//     index guard). POFF padding kills the 4-way b128 bank conflicts.

#define POFF(i) ((i) + (((i) >> 5) << 2))   // 4-float pad every 32 floats

__global__ __launch_bounds__(256, 1) void pfaffian_kernel(
    const float* __restrict__ x,    // [128, 128]
    const float* __restrict__ F,    // [32640] packed strict lower tri of 256x256
    float* __restrict__ out)        // [128]
{
    const int b    = blockIdx.x;
    const int t    = threadIdx.x;
    const int lane = t & 63;
    const int wave = t >> 6;

    __shared__ int idx_sh[128];
    __shared__ int wtot[4];
    __shared__ __align__(16) float bufT[2][144];  // tau (padded, 0 on dead idx)
    __shared__ __align__(16) float bufC[2][144];  // col  (padded, 0 on dead idx)
    __shared__ float pivbuf[2];

    // ---- occupancy -> sorted index list (certified rounds 0-8) ----
    const float xv  = x[b * 128 + (t & 127)];
    const bool  pos = xv > 0.0f;
    const bool  o   = (t < 128) ? pos : !pos;

    const unsigned long long m = __ballot(o);
    const int rank = __popcll(m & ((1ull << lane) - 1ull));
    if (lane == 63) wtot[wave] = rank + (o ? 1 : 0);
    __syncthreads();
    int off = 0;
#pragma unroll
    for (int w = 0; w < 4; ++w)
        if (w < wave) off += wtot[w];
    if (o) idx_sh[off + rank] = t;
    __syncthreads();

    // ---- 8x8 block ownership ----
    const int r8   = t >> 4;        // row group: rows [r8*8, r8*8+8)
    const int c8   = t & 15;        // col group: cols [c8*8, c8*8+8)
    const int row0 = r8 * 8;
    const int col0 = c8 * 8;
    const int prow = POFF(row0);    // padded offsets (groups stay contiguous)
    const int pcol = POFF(col0);

    int ri[8], ci[8];
#pragma unroll
    for (int a = 0; a < 8; ++a) ri[a] = idx_sh[row0 + a];
#pragma unroll
    for (int c = 0; c < 8; ++c) ci[c] = idx_sh[col0 + c];

    // ---- gather A[a][c] = F_full[ri[a]][ci[c]] (all indices compile-time) ----
    float A[8][8];
#pragma unroll
    for (int a = 0; a < 8; ++a) {
        const int ii = ri[a];
#pragma unroll
        for (int c = 0; c < 8; ++c) {
            const int jj = ci[c];
            const int hi = ii > jj ? ii : jj;
            const int lo = ii > jj ? jj : ii;
            float v = (ii == jj) ? 0.0f : F[(hi * (hi - 1)) / 2 + lo];
            A[a][c] = (ii < jj) ? -v : v;
        }
    }

    // ---- seed step 0: piv0 = A[0][1] (owner t=0), then tau0/col0 into buf 0
    if (t == 0) pivbuf[0] = A[0][1];
    __syncthreads();
    {
        const float piv0 = pivbuf[0];
        if (r8 == 0) {               // tau publishers for step 0 (row 0)
            float v[8];
#pragma unroll
            for (int j = 0; j < 8; ++j) {
                const int cj = col0 + j;
                v[j] = (cj > 1) ? __fdiv_rn(A[0][j], piv0) : 0.0f;
            }
            *(float4*)&bufT[0][pcol]     = make_float4(v[0], v[1], v[2], v[3]);
            *(float4*)&bufT[0][pcol + 4] = make_float4(v[4], v[5], v[6], v[7]);
        }
        if (c8 == 0) {               // col publishers for step 0 (col 1)
            float v[8];
#pragma unroll
            for (int j = 0; j < 8; ++j) {
                const int rj = row0 + j;
                v[j] = (rj > 1) ? A[j][1] : 0.0f;
            }
            *(float4*)&bufC[0][prow]     = make_float4(v[0], v[1], v[2], v[3]);
            *(float4*)&bufC[0][prow + 4] = make_float4(v[4], v[5], v[6], v[7]);
        }
    }
    __syncthreads();

    // ---- 64 steps, ONE barrier each; s unrolled -> parity & A idx compile-time
    float pf = 1.0f;
    for (int ib = 0; ib < 16; ++ib) {
#pragma unroll
        for (int s = 0; s < 4; ++s) {
            const int i   = ib * 4 + s;
            const int k   = 8 * ib + 2 * s;
            const int kp1 = k + 1;
            const int p   = s & 1;        // == i & 1, compile-time
            const int q   = 1 - p;

            const float piv = pivbuf[p];  // written step i-1, ordered by barrier
            pf = __fmul_rn(pf, piv);      // OUTSIDE early-out: t0's wave dies early

            if (wave * 32 + 31 > kp1) {   // wave-uniform: any of my rows alive
                // load step-i vectors (padded layout: col reads <=2-way = free)
                float4 tr0 = *(const float4*)&bufT[p][prow];
                float4 tr1 = *(const float4*)&bufT[p][prow + 4];
                float4 cr0 = *(const float4*)&bufC[p][prow];
                float4 cr1 = *(const float4*)&bufC[p][prow + 4];
                float4 tc0 = *(const float4*)&bufT[p][pcol];
                float4 tc1 = *(const float4*)&bufT[p][pcol + 4];
                float4 cc0 = *(const float4*)&bufC[p][pcol];
                float4 cc1 = *(const float4*)&bufC[p][pcol + 4];

                float tr[8] = {tr0.x, tr0.y, tr0.z, tr0.w, tr1.x, tr1.y, tr1.z, tr1.w};
                float cr[8] = {cr0.x, cr0.y, cr0.z, cr0.w, cr1.x, cr1.y, cr1.z, cr1.w};
                float tc[8] = {tc0.x, tc0.y, tc0.z, tc0.w, tc1.x, tc1.y, tc1.z, tc1.w};
                float cc[8] = {cc0.x, cc0.y, cc0.z, cc0.w, cc1.x, cc1.y, cc1.z, cc1.w};

                float ncr[8];
#pragma unroll
                for (int a = 0; a < 8; ++a) ncr[a] = -cr[a];

                // rank-2 update (dead entries: zeros-trick identity)
#pragma unroll
                for (int a = 0; a < 8; ++a) {
#pragma unroll
                    for (int c = 0; c < 8; ++c) {
                        const float tmp = __fmaf_rn(tr[a], cc[c], A[a][c]);
                        A[a][c] = __fmaf_rn(ncr[a], tc[c], tmp);
                    }
                }

                // ---- publish step i+1 into buf q (post-update register values)
                if (i < 63) {
                    const int ntg = (k + 2) >> 3;   // next tau (row) group
                    const int ncg = (k + 3) >> 3;   // next col group
                    if (r8 == ntg) {
                        // forward next pivot in-register within this wave:
                        // owner lane holds updated A[(k+2)&7][(k+3)&7]
                        const int ownerLane = ((ntg << 4) + ncg) & 63;
                        const float newpiv =
                            __shfl(A[(2 * s + 2) & 7][(2 * s + 3) & 7], ownerLane);
                        if (c8 == ncg) pivbuf[q] = newpiv;   // owner stores it
                        float v[8];
#pragma unroll
                        for (int j = 0; j < 8; ++j) {
                            const int cj = col0 + j;
                            v[j] = (cj > k + 3)
                                 ? __fdiv_rn(A[(2 * s + 2) & 7][j], newpiv)
                                 : 0.0f;
                        }
                        *(float4*)&bufT[q][pcol]     = make_float4(v[0], v[1], v[2], v[3]);
                        *(float4*)&bufT[q][pcol + 4] = make_float4(v[4], v[5], v[6], v[7]);
                    }
                    if (c8 == ncg) {
                        float v[8];
#pragma unroll
                        for (int j = 0; j < 8; ++j) {
                            const int rj = row0 + j;
                            v[j] = (rj > k + 3) ? A[j][(2 * s + 3) & 7] : 0.0f;
                        }
                        *(float4*)&bufC[q][prow]     = make_float4(v[0], v[1], v[2], v[3]);
                        *(float4*)&bufC[q][prow + 4] = make_float4(v[4], v[5], v[6], v[7]);
                    }
                }
            }
            __syncthreads();   // the ONLY barrier per step
        }
    }

    if (t == 0) out[b] = pf;
}

extern "C" void kernel_launch(void* const* d_in, const int* in_sizes, int n_in,
                              void* d_out, int out_size, void* d_ws, size_t ws_size,
                              hipStream_t stream) {
    const float* x = (const float*)d_in[0];   // [128*128]
    const float* F = (const float*)d_in[1];   // [32640]
    float* out     = (float*)d_out;           // [128]
    (void)in_sizes; (void)n_in; (void)out_size; (void)d_ws; (void)ws_size;

    pfaffian_kernel<<<128, 256, 0, stream>>>(x, F, out);
}